// Round 8
// baseline (93.570 us; speedup 1.0000x reference)
//
#include <hip/hip_runtime.h>
#include <math.h>

// Problem constants (match reference)
#define B_ 2
#define T_ 2048
#define M_ 768
#define R_ 64
#define S_ 16
#define MS_ (M_ * S_)
#define NC 128
#define CL 16              // T_ / NC
#define LOG2E 1.4426950408889634f
#define LOG2_EPS (-33.219280948873623f)   // log2(1e-10) = LOG_EPS * LOG2E

// --------------------------------------------------------------------------
// Kernel 1 (bc v6, round-5 verified): register-cached W. Wave holds 4 s-rows
// of W (48 VGPR) and processes 8 bt rows (acc[32] = 8 rows x 4 s).
// Block = 512 thr / 8 waves covering all 32 s. Fold+pack butterfly reduce.
// --------------------------------------------------------------------------
__global__ __launch_bounds__(512, 4) void bc_kernel(
    const float* __restrict__ u,     // [B*T][M]
    const float* __restrict__ B_w,   // [S][M]
    const float* __restrict__ C_w,   // [S][M]
    float* __restrict__ Bm,          // [B*T][S]
    float* __restrict__ Cm)          // [B*T][S]
{
  const int wave = threadIdx.x >> 6, lane = threadIdx.x & 63;
  const int bt0 = blockIdx.x * 8;

  float4 w[4][3];
  #pragma unroll
  for (int s = 0; s < 4; ++s) {
    const int s_g = wave * 4 + s;
    const float* wr = (s_g < 16) ? &B_w[(size_t)s_g * M_] : &C_w[(size_t)(s_g - 16) * M_];
    const float4* w4 = reinterpret_cast<const float4*>(wr);
    w[s][0] = w4[lane]; w[s][1] = w4[64 + lane]; w[s][2] = w4[128 + lane];
  }

  float acc[32];
  #pragma unroll
  for (int r = 0; r < 8; ++r) {
    const float4* ur = reinterpret_cast<const float4*>(&u[(size_t)(bt0 + r) * M_]);
    const float4 a0 = ur[lane], a1 = ur[64 + lane], a2 = ur[128 + lane];
    #pragma unroll
    for (int s = 0; s < 4; ++s) {
      float t = 0.f;
      t = fmaf(a0.x, w[s][0].x, t); t = fmaf(a0.y, w[s][0].y, t);
      t = fmaf(a0.z, w[s][0].z, t); t = fmaf(a0.w, w[s][0].w, t);
      t = fmaf(a1.x, w[s][1].x, t); t = fmaf(a1.y, w[s][1].y, t);
      t = fmaf(a1.z, w[s][1].z, t); t = fmaf(a1.w, w[s][1].w, t);
      t = fmaf(a2.x, w[s][2].x, t); t = fmaf(a2.y, w[s][2].y, t);
      t = fmaf(a2.z, w[s][2].z, t); t = fmaf(a2.w, w[s][2].w, t);
      acc[r * 4 + s] = t;
    }
  }

  #pragma unroll
  for (int j = 0; j < 32; ++j) acc[j] += __shfl_xor(acc[j], 32);
  int cnt = 32;
  #pragma unroll
  for (int mask = 16; mask >= 1; mask >>= 1) {
    cnt >>= 1;
    const bool up = (lane & mask) != 0;
    #pragma unroll
    for (int j = 0; j < cnt; ++j) {
      float give = up ? acc[j] : acc[j + cnt];
      float keep = up ? acc[j + cnt] : acc[j];
      acc[j] = keep + __shfl_xor(give, mask);
    }
  }

  if (lane < 32) {
    const int r = lane >> 2, s_l = lane & 3;
    const int s_g = wave * 4 + s_l;
    const int bt = bt0 + r;
    if (s_g < 16) Bm[(size_t)bt * S_ + s_g] = acc[0];
    else          Cm[(size_t)bt * S_ + (s_g - 16)] = acc[0];
  }
}

// --------------------------------------------------------------------------
// Kernels 2 & 4: fused dt-GEMM + chunk-local scan, NC=128 (CL=16).
// Block = (m-tile 64, chunk, b), 128 thr = 2 waves = 64 m x 2 s-halves.
// dt computed in-kernel into LDS (never in HBM). delta tile time-shares one
// 4 KB scratch with bm/cm. LDS 12 KB -> grid-limited 12 blocks/CU (24 w/CU).
// exp2-folded decay: A2 = clip(-exp(A_log)) * log2e, clamp at log2(1e-10).
// Summaries [B][NC][S][M] coalesced per m. Aprod doubles as carry buffer.
// --------------------------------------------------------------------------
template <int PHASE>
__global__ __launch_bounds__(128) void scan_fused(
    const float* __restrict__ u,       // [B*T][M]
    const float* __restrict__ delta,   // [B*T][R]
    const float* __restrict__ dt_w,    // [M][R]
    const float* __restrict__ dt_b,    // [M]
    const float* __restrict__ Bm,      // [B*T][S]
    const float* __restrict__ Cm,      // [B*T][S]
    const float* __restrict__ A_log,   // [S][M]
    const float* __restrict__ D,       // [M]
    float* __restrict__ Aprod,         // [B][NC][S][M]; carry after kernel 3
    float* __restrict__ Hend,          // [B][NC][S][M]
    float* __restrict__ out)           // [B*T][M]
{
  __shared__ float u_lds[CL][64];      // 4 KB
  __shared__ float dt_lds[CL][64];     // 4 KB
  __shared__ float scratch[CL * 64];   // 4 KB: delta_s[16][64] -> bm[256]|cm[256]

  const int tid = threadIdx.x;
  const int mt = blockIdx.x;               // 0..11
  const int c  = blockIdx.y;               // 0..127
  const int b  = blockIdx.z;
  const int m0 = mt * 64;
  const int t0 = c * CL;
  const size_t row0 = (size_t)b * T_ + t0;

  // ---- stage delta [16][64] + u [16][64], coalesced float4 ----
  {
    float (*delta_s)[64] = reinterpret_cast<float (*)[64]>(scratch);
    #pragma unroll
    for (int p = 0; p < 2; ++p) {
      const int i4 = tid + p * 128;        // 256 float4 each
      const int t = i4 >> 4, c4 = (i4 & 15) * 4;
      *reinterpret_cast<float4*>(&delta_s[t][c4]) =
          *reinterpret_cast<const float4*>(&delta[(row0 + t) * R_ + c4]);
      *reinterpret_cast<float4*>(&u_lds[t][c4]) =
          *reinterpret_cast<const float4*>(&u[(row0 + t) * M_ + m0 + c4]);
    }
  }

  // ---- A2 column (global loads independent of LDS; overlaps staging) ----
  const int lane = tid & 63, wv = tid >> 6;
  const int m_l = wv * 32 + (lane & 31);     // 0..63
  const int sh = lane >> 5, s0 = sh * 8;
  const int m = m0 + m_l;
  float A2[8];
  #pragma unroll
  for (int s = 0; s < 8; ++s) {
    const float a = -__expf(A_log[(size_t)(s0 + s) * M_ + m]);
    A2[s] = fminf(fmaxf(a, -10.f), -1e-6f) * LOG2E;
  }
  __syncthreads();

  // ---- dt tile: clip(softplus(delta . dt_w[m]^T + b)) -> dt_lds ----
  {
    float (*delta_s)[64] = reinterpret_cast<float (*)[64]>(scratch);
    const int ml2 = tid & 63, th = tid >> 6;   // thread: m=m0+ml2, t-half th
    float acc[8] = {};
    const float* wrow = &dt_w[(size_t)(m0 + ml2) * R_];
    #pragma unroll
    for (int r4 = 0; r4 < R_; r4 += 4) {
      const float4 w4 = *reinterpret_cast<const float4*>(&wrow[r4]);
      #pragma unroll
      for (int i = 0; i < 8; ++i) {
        const float4 d4 = *reinterpret_cast<const float4*>(&delta_s[th * 8 + i][r4]);
        acc[i] = fmaf(d4.x, w4.x, acc[i]);
        acc[i] = fmaf(d4.y, w4.y, acc[i]);
        acc[i] = fmaf(d4.z, w4.z, acc[i]);
        acc[i] = fmaf(d4.w, w4.w, acc[i]);
      }
    }
    const float bias = dt_b[m0 + ml2];
    #pragma unroll
    for (int i = 0; i < 8; ++i) {
      const float x = acc[i] + bias;
      const float sp = (x > 20.f) ? x : __logf(1.f + __expf(x));
      dt_lds[th * 8 + i][ml2] = fminf(fmaxf(sp, 1e-6f), 10.f);
    }
  }
  __syncthreads();   // delta_s dead

  // ---- stage bm/cm into scratch (reuse) ----
  float* bm_lds = scratch;            // [16][16]
  float* cm_lds = scratch + CL * S_;
  {
    const size_t bcb = row0 * S_;
    #pragma unroll
    for (int p = 0; p < 2; ++p) {
      const int idx = tid + p * 128;
      bm_lds[idx] = Bm[bcb + idx];
      if constexpr (PHASE == 3) cm_lds[idx] = Cm[bcb + idx];
    }
  }

  float h[8], Sla[8], Dm = 0.f;
  const size_t smb = (((size_t)b * NC + c) * S_ + s0) * M_ + m;
  if constexpr (PHASE == 1) {
    #pragma unroll
    for (int s = 0; s < 8; ++s) { h[s] = 0.f; Sla[s] = 0.f; }
  } else {
    #pragma unroll
    for (int s = 0; s < 8; ++s) h[s] = Aprod[smb + (size_t)s * M_];  // carry
    Dm = D[m];
  }
  __syncthreads();

  // ---- serial recurrence over the chunk (LDS-only operands) ----
  #pragma unroll
  for (int t = 0; t < CL; ++t) {
    const float dtv = dt_lds[t][m_l];
    const float uv  = u_lds[t][m_l];
    const float du  = dtv * uv;
    const float4 bv0 = *reinterpret_cast<const float4*>(&bm_lds[t * S_ + s0]);
    const float4 bv1 = *reinterpret_cast<const float4*>(&bm_lds[t * S_ + s0 + 4]);
    const float bmv[8] = {bv0.x, bv0.y, bv0.z, bv0.w, bv1.x, bv1.y, bv1.z, bv1.w};
    float cmv[8];
    if constexpr (PHASE == 3) {
      const float4 cv0 = *reinterpret_cast<const float4*>(&cm_lds[t * S_ + s0]);
      const float4 cv1 = *reinterpret_cast<const float4*>(&cm_lds[t * S_ + s0 + 4]);
      cmv[0] = cv0.x; cmv[1] = cv0.y; cmv[2] = cv0.z; cmv[3] = cv0.w;
      cmv[4] = cv1.x; cmv[5] = cv1.y; cmv[6] = cv1.z; cmv[7] = cv1.w;
    }
    float y = 0.f;
    #pragma unroll
    for (int s = 0; s < 8; ++s) {
      const float la = fmaxf(dtv * A2[s], LOG2_EPS);   // log2-domain decay
      const float e  = exp2f(la);                      // v_exp_f32 directly
      h[s] = fmaf(e, h[s], du * bmv[s]);
      if constexpr (PHASE == 1) Sla[s] += la;          // log-sum (matches ref cumsum)
      else y = fmaf(h[s], cmv[s], y);
    }
    if constexpr (PHASE == 3) {
      y += __shfl_xor(y, 32);
      if (sh == 0) {
        const float o = y + uv * Dm;
        out[(row0 + t) * M_ + m] = fminf(fmaxf(o, -1e4f), 1e4f);
      }
    }
  }

  if constexpr (PHASE == 1) {
    #pragma unroll
    for (int s = 0; s < 8; ++s) {
      Aprod[smb + (size_t)s * M_] = exp2f(Sla[s]);     // chunk decay product
      Hend[smb + (size_t)s * M_]  = h[s];
    }
  }
}

// --------------------------------------------------------------------------
// Kernel 3: chunk-carry combine, in place: Aprod[c] is read (decay product)
// then overwritten with the carry (h-state entering chunk c).
// --------------------------------------------------------------------------
__global__ __launch_bounds__(256) void carry_kernel(
    float* __restrict__ Aprod, const float* __restrict__ Hend)
{
  const int idx = blockIdx.x * 256 + threadIdx.x;  // over B*S*M
  const int b = idx / MS_;
  const int sm = idx - b * MS_;
  float h = 0.f;
  #pragma unroll 16
  for (int c = 0; c < NC; ++c) {
    const size_t o = ((size_t)b * NC + c) * MS_ + sm;
    const float a  = Aprod[o];
    const float he = Hend[o];
    Aprod[o] = h;                 // carry into chunk c
    h = fmaf(a, h, he);
  }
}

// --------------------------------------------------------------------------
extern "C" void kernel_launch(void* const* d_in, const int* in_sizes, int n_in,
                              void* d_out, int out_size, void* d_ws, size_t ws_size,
                              hipStream_t stream)
{
  const float* u     = (const float*)d_in[0];
  const float* delta = (const float*)d_in[1];
  const float* dt_w  = (const float*)d_in[2];
  const float* dt_b  = (const float*)d_in[3];
  const float* A_log = (const float*)d_in[4];
  const float* B_w   = (const float*)d_in[5];
  const float* C_w   = (const float*)d_in[6];
  const float* D     = (const float*)d_in[7];
  float* out = (float*)d_out;
  float* ws  = (float*)d_ws;

  const size_t fl_bc = (size_t)B_ * T_ * S_;   // 65,536
  const size_t fl_sm = (size_t)B_ * NC * MS_;  // 3,145,728

  float* Bm    = ws;
  float* Cm    = Bm + fl_bc;
  float* Aprod = Cm + fl_bc;         // later holds carries
  float* Hend  = Aprod + fl_sm;      // total ~25.7 MB

  bc_kernel<<<dim3((B_ * T_) / 8), 512, 0, stream>>>(u, B_w, C_w, Bm, Cm);
  scan_fused<1><<<dim3(M_ / 64, NC, B_), 128, 0, stream>>>(
      u, delta, dt_w, dt_b, Bm, Cm, A_log, D, Aprod, Hend, nullptr);
  carry_kernel<<<dim3((B_ * MS_) / 256), 256, 0, stream>>>(Aprod, Hend);
  scan_fused<3><<<dim3(M_ / 64, NC, B_), 128, 0, stream>>>(
      u, delta, dt_w, dt_b, Bm, Cm, A_log, D, Aprod, Hend, out);
}

// Round 9
// 85.315 us; speedup vs baseline: 1.0968x; 1.0968x over previous
//
#include <hip/hip_runtime.h>
#include <math.h>

// Problem constants (match reference)
#define B_ 2
#define T_ 2048
#define M_ 768
#define R_ 64
#define S_ 16
#define MS_ (M_ * S_)
#define NC 64              // summary chunks (32 t each)
#define HL 16              // half-chunk staged at a time
#define LOG2E 1.4426950408889634f
#define LOG2_EPS (-33.219280948873623f)   // log2(1e-10)

// --------------------------------------------------------------------------
// Kernel 1 (round-5 proven): dt = clip(softplus(delta . dt_w^T + b)).
// Tiled 64x64, K=64, LDS transpose staging, coalesced everywhere.
// --------------------------------------------------------------------------
__global__ __launch_bounds__(256) void dt_kernel(
    const float* __restrict__ delta,   // [B*T][R]
    const float* __restrict__ dt_w,    // [M][R]
    const float* __restrict__ dt_b,    // [M]
    float* __restrict__ dt_out)        // [B*T][M]
{
  __shared__ float ds_d[R_][68];
  __shared__ float ds_w[R_][68];
  const int tid = threadIdx.x;
  const int m0  = blockIdx.x * 64;
  const int bt0 = blockIdx.y * 64;

  #pragma unroll
  for (int k = 0; k < 4; ++k) {
    int idx = tid + k * 256;
    int rq = idx & 15;
    int x  = idx >> 4;
    float4 dv = *reinterpret_cast<const float4*>(&delta[(size_t)(bt0 + x) * R_ + rq * 4]);
    ds_d[rq * 4 + 0][x] = dv.x; ds_d[rq * 4 + 1][x] = dv.y;
    ds_d[rq * 4 + 2][x] = dv.z; ds_d[rq * 4 + 3][x] = dv.w;
    float4 wv = *reinterpret_cast<const float4*>(&dt_w[(size_t)(m0 + x) * R_ + rq * 4]);
    ds_w[rq * 4 + 0][x] = wv.x; ds_w[rq * 4 + 1][x] = wv.y;
    ds_w[rq * 4 + 2][x] = wv.z; ds_w[rq * 4 + 3][x] = wv.w;
  }
  __syncthreads();

  const int mq = tid & 15, tq = tid >> 4;
  const int ml = mq * 4, tl = tq * 4;
  float acc[4][4] = {};
  #pragma unroll 4
  for (int r = 0; r < R_; ++r) {
    float4 dv = *reinterpret_cast<const float4*>(&ds_d[r][tl]);
    float4 wv = *reinterpret_cast<const float4*>(&ds_w[r][ml]);
    float d[4] = {dv.x, dv.y, dv.z, dv.w};
    float w[4] = {wv.x, wv.y, wv.z, wv.w};
    #pragma unroll
    for (int i = 0; i < 4; ++i)
      #pragma unroll
      for (int j = 0; j < 4; ++j)
        acc[i][j] = fmaf(d[i], w[j], acc[i][j]);
  }

  float4 bb = *reinterpret_cast<const float4*>(&dt_b[m0 + ml]);
  float bv[4] = {bb.x, bb.y, bb.z, bb.w};
  #pragma unroll
  for (int i = 0; i < 4; ++i) {
    float4 o;
    float* op = &o.x;
    #pragma unroll
    for (int j = 0; j < 4; ++j) {
      float x = acc[i][j] + bv[j];
      float sp = (x > 20.f) ? x : __logf(1.f + __expf(x));
      op[j] = fminf(fmaxf(sp, 1e-6f), 10.f);
    }
    *reinterpret_cast<float4*>(&dt_out[(size_t)(bt0 + tl + i) * M_ + m0 + ml]) = o;
  }
}

// --------------------------------------------------------------------------
// Kernel 2 (bc v6, proven): register-cached W slices, fold+pack butterfly.
// --------------------------------------------------------------------------
__global__ __launch_bounds__(512, 4) void bc_kernel(
    const float* __restrict__ u,     // [B*T][M]
    const float* __restrict__ B_w,   // [S][M]
    const float* __restrict__ C_w,   // [S][M]
    float* __restrict__ Bm,          // [B*T][S]
    float* __restrict__ Cm)          // [B*T][S]
{
  const int wave = threadIdx.x >> 6, lane = threadIdx.x & 63;
  const int bt0 = blockIdx.x * 8;

  float4 w[4][3];
  #pragma unroll
  for (int s = 0; s < 4; ++s) {
    const int s_g = wave * 4 + s;
    const float* wr = (s_g < 16) ? &B_w[(size_t)s_g * M_] : &C_w[(size_t)(s_g - 16) * M_];
    const float4* w4 = reinterpret_cast<const float4*>(wr);
    w[s][0] = w4[lane]; w[s][1] = w4[64 + lane]; w[s][2] = w4[128 + lane];
  }

  float acc[32];
  #pragma unroll
  for (int r = 0; r < 8; ++r) {
    const float4* ur = reinterpret_cast<const float4*>(&u[(size_t)(bt0 + r) * M_]);
    const float4 a0 = ur[lane], a1 = ur[64 + lane], a2 = ur[128 + lane];
    #pragma unroll
    for (int s = 0; s < 4; ++s) {
      float t = 0.f;
      t = fmaf(a0.x, w[s][0].x, t); t = fmaf(a0.y, w[s][0].y, t);
      t = fmaf(a0.z, w[s][0].z, t); t = fmaf(a0.w, w[s][0].w, t);
      t = fmaf(a1.x, w[s][1].x, t); t = fmaf(a1.y, w[s][1].y, t);
      t = fmaf(a1.z, w[s][1].z, t); t = fmaf(a1.w, w[s][1].w, t);
      t = fmaf(a2.x, w[s][2].x, t); t = fmaf(a2.y, w[s][2].y, t);
      t = fmaf(a2.z, w[s][2].z, t); t = fmaf(a2.w, w[s][2].w, t);
      acc[r * 4 + s] = t;
    }
  }

  #pragma unroll
  for (int j = 0; j < 32; ++j) acc[j] += __shfl_xor(acc[j], 32);
  int cnt = 32;
  #pragma unroll
  for (int mask = 16; mask >= 1; mask >>= 1) {
    cnt >>= 1;
    const bool up = (lane & mask) != 0;
    #pragma unroll
    for (int j = 0; j < cnt; ++j) {
      float give = up ? acc[j] : acc[j + cnt];
      float keep = up ? acc[j + cnt] : acc[j];
      acc[j] = keep + __shfl_xor(give, mask);
    }
  }

  if (lane < 32) {
    const int r = lane >> 2, s_l = lane & 3;
    const int s_g = wave * 4 + s_l;
    const int bt = bt0 + r;
    if (s_g < 16) Bm[(size_t)bt * S_ + s_g] = acc[0];
    else          Cm[(size_t)bt * S_ + (s_g - 16)] = acc[0];
  }
}

// --------------------------------------------------------------------------
// Kernels 3 & 5 (scan v6): block = (m-tile 64, chunk of 32 t, b), 128 thr.
// The 32 steps run as two 16-step halves: half-0 staged to LDS, then half-1's
// global loads are issued into REGISTERS and written to the second LDS buffer
// after half-0's scan (HBM latency hidden under 16 steps of compute).
// h carries continuously across halves -> one summary per 32-step chunk.
// exp2-domain decay. Summaries [B][NC][S][M]; Aprod doubles as carry buffer.
// --------------------------------------------------------------------------
template <int PHASE>
__global__ __launch_bounds__(128) void scan_v6(
    const float* __restrict__ dt_ws,   // [B*T][M]
    const float* __restrict__ u,       // [B*T][M]
    const float* __restrict__ Bm,      // [B*T][S]
    const float* __restrict__ Cm,      // [B*T][S]
    const float* __restrict__ A_log,   // [S][M]
    const float* __restrict__ D,       // [M]
    float* __restrict__ Aprod,         // [B][NC][S][M]; carry after kernel 4
    float* __restrict__ Hend,          // [B][NC][S][M]
    float* __restrict__ out)           // [B*T][M]
{
  __shared__ float u0_lds[HL][64], u1_lds[HL][64];     // 4 KB each
  __shared__ float d0_lds[HL][64], d1_lds[HL][64];
  __shared__ float bm0[HL * S_], bm1[HL * S_];         // 1 KB each
  __shared__ float cm0[HL * S_], cm1[HL * S_];

  const int tid = threadIdx.x;
  const int mt = blockIdx.x;               // 0..11
  const int c  = blockIdx.y;               // 0..63
  const int b  = blockIdx.z;
  const int m0 = mt * 64;
  const int t0 = c * 32;
  const size_t row0 = (size_t)b * T_ + t0;

  const int lane = tid & 63, wv = tid >> 6;
  const int m_l = wv * 32 + (lane & 31);   // 0..63
  const int sh = lane >> 5, s0 = sh * 8;
  const int m = m0 + m_l;

  // staging map for a 16x64 tile: p in {0,1}: i4=tid+p*128, t=i4>>4, m4=(i4&15)*4
  const int st0 = tid >> 4, sm4 = (tid & 15) * 4;
  const int st1 = (tid + 128) >> 4, sm41 = ((tid + 128) & 15) * 4;

  // ---- stage half 0 ----
  *reinterpret_cast<float4*>(&u0_lds[st0][sm4]) =
      *reinterpret_cast<const float4*>(&u[(row0 + st0) * M_ + m0 + sm4]);
  *reinterpret_cast<float4*>(&u0_lds[st1][sm41]) =
      *reinterpret_cast<const float4*>(&u[(row0 + st1) * M_ + m0 + sm41]);
  *reinterpret_cast<float4*>(&d0_lds[st0][sm4]) =
      *reinterpret_cast<const float4*>(&dt_ws[(row0 + st0) * M_ + m0 + sm4]);
  *reinterpret_cast<float4*>(&d0_lds[st1][sm41]) =
      *reinterpret_cast<const float4*>(&dt_ws[(row0 + st1) * M_ + m0 + sm41]);
  {
    const size_t bcb = row0 * S_;
    bm0[tid]       = Bm[bcb + tid];
    bm0[tid + 128] = Bm[bcb + tid + 128];
    if constexpr (PHASE == 3) {
      cm0[tid]       = Cm[bcb + tid];
      cm0[tid + 128] = Cm[bcb + tid + 128];
    }
  }

  // ---- A2 (coalesced per s), carry load (PHASE 3) ----
  float A2[8];
  #pragma unroll
  for (int s = 0; s < 8; ++s) {
    const float a = -__expf(A_log[(size_t)(s0 + s) * M_ + m]);
    A2[s] = fminf(fmaxf(a, -10.f), -1e-6f) * LOG2E;
  }
  float h[8], Sla[8], Dm = 0.f;
  const size_t smb = (((size_t)b * NC + c) * S_ + s0) * M_ + m;
  if constexpr (PHASE == 1) {
    #pragma unroll
    for (int s = 0; s < 8; ++s) { h[s] = 0.f; Sla[s] = 0.f; }
  } else {
    #pragma unroll
    for (int s = 0; s < 8; ++s) h[s] = Aprod[smb + (size_t)s * M_];  // carry
    Dm = D[m];
  }
  __syncthreads();

  // ---- issue half-1 global loads into registers (latency hides under scan0)
  const size_t row1 = row0 + HL;
  const float4 pu0 = *reinterpret_cast<const float4*>(&u[(row1 + st0) * M_ + m0 + sm4]);
  const float4 pu1 = *reinterpret_cast<const float4*>(&u[(row1 + st1) * M_ + m0 + sm41]);
  const float4 pd0 = *reinterpret_cast<const float4*>(&dt_ws[(row1 + st0) * M_ + m0 + sm4]);
  const float4 pd1 = *reinterpret_cast<const float4*>(&dt_ws[(row1 + st1) * M_ + m0 + sm41]);
  const size_t bcb1 = row1 * S_;
  const float pb0 = Bm[bcb1 + tid];
  const float pb1 = Bm[bcb1 + tid + 128];
  float pc0 = 0.f, pc1 = 0.f;
  if constexpr (PHASE == 3) {
    pc0 = Cm[bcb1 + tid];
    pc1 = Cm[bcb1 + tid + 128];
  }

  // ---- scan half 0 ----
  #pragma unroll
  for (int t = 0; t < HL; ++t) {
    const float dtv = d0_lds[t][m_l];
    const float uv  = u0_lds[t][m_l];
    const float du  = dtv * uv;
    const float4 bv0 = *reinterpret_cast<const float4*>(&bm0[t * S_ + s0]);
    const float4 bv1 = *reinterpret_cast<const float4*>(&bm0[t * S_ + s0 + 4]);
    const float bmv[8] = {bv0.x, bv0.y, bv0.z, bv0.w, bv1.x, bv1.y, bv1.z, bv1.w};
    float cmv[8];
    if constexpr (PHASE == 3) {
      const float4 cv0 = *reinterpret_cast<const float4*>(&cm0[t * S_ + s0]);
      const float4 cv1 = *reinterpret_cast<const float4*>(&cm0[t * S_ + s0 + 4]);
      cmv[0] = cv0.x; cmv[1] = cv0.y; cmv[2] = cv0.z; cmv[3] = cv0.w;
      cmv[4] = cv1.x; cmv[5] = cv1.y; cmv[6] = cv1.z; cmv[7] = cv1.w;
    }
    float y = 0.f;
    #pragma unroll
    for (int s = 0; s < 8; ++s) {
      const float la = fmaxf(dtv * A2[s], LOG2_EPS);
      const float e  = exp2f(la);
      h[s] = fmaf(e, h[s], du * bmv[s]);
      if constexpr (PHASE == 1) Sla[s] += la;
      else y = fmaf(h[s], cmv[s], y);
    }
    if constexpr (PHASE == 3) {
      y += __shfl_xor(y, 32);
      if (sh == 0) {
        const float o = y + uv * Dm;
        out[(row0 + t) * M_ + m] = fminf(fmaxf(o, -1e4f), 1e4f);
      }
    }
  }

  // ---- write prefetched half-1 into second LDS buffer ----
  *reinterpret_cast<float4*>(&u1_lds[st0][sm4])  = pu0;
  *reinterpret_cast<float4*>(&u1_lds[st1][sm41]) = pu1;
  *reinterpret_cast<float4*>(&d1_lds[st0][sm4])  = pd0;
  *reinterpret_cast<float4*>(&d1_lds[st1][sm41]) = pd1;
  bm1[tid] = pb0; bm1[tid + 128] = pb1;
  if constexpr (PHASE == 3) { cm1[tid] = pc0; cm1[tid + 128] = pc1; }
  __syncthreads();

  // ---- scan half 1 (h carries over) ----
  #pragma unroll
  for (int t = 0; t < HL; ++t) {
    const float dtv = d1_lds[t][m_l];
    const float uv  = u1_lds[t][m_l];
    const float du  = dtv * uv;
    const float4 bv0 = *reinterpret_cast<const float4*>(&bm1[t * S_ + s0]);
    const float4 bv1 = *reinterpret_cast<const float4*>(&bm1[t * S_ + s0 + 4]);
    const float bmv[8] = {bv0.x, bv0.y, bv0.z, bv0.w, bv1.x, bv1.y, bv1.z, bv1.w};
    float cmv[8];
    if constexpr (PHASE == 3) {
      const float4 cv0 = *reinterpret_cast<const float4*>(&cm1[t * S_ + s0]);
      const float4 cv1 = *reinterpret_cast<const float4*>(&cm1[t * S_ + s0 + 4]);
      cmv[0] = cv0.x; cmv[1] = cv0.y; cmv[2] = cv0.z; cmv[3] = cv0.w;
      cmv[4] = cv1.x; cmv[5] = cv1.y; cmv[6] = cv1.z; cmv[7] = cv1.w;
    }
    float y = 0.f;
    #pragma unroll
    for (int s = 0; s < 8; ++s) {
      const float la = fmaxf(dtv * A2[s], LOG2_EPS);
      const float e  = exp2f(la);
      h[s] = fmaf(e, h[s], du * bmv[s]);
      if constexpr (PHASE == 1) Sla[s] += la;
      else y = fmaf(h[s], cmv[s], y);
    }
    if constexpr (PHASE == 3) {
      y += __shfl_xor(y, 32);
      if (sh == 0) {
        const float o = y + uv * Dm;
        out[(row1 + t) * M_ + m] = fminf(fmaxf(o, -1e4f), 1e4f);
      }
    }
  }

  if constexpr (PHASE == 1) {
    #pragma unroll
    for (int s = 0; s < 8; ++s) {
      Aprod[smb + (size_t)s * M_] = exp2f(Sla[s]);   // 32-step decay product
      Hend[smb + (size_t)s * M_]  = h[s];
    }
  }
}

// --------------------------------------------------------------------------
// Kernel 4: chunk-carry combine, in place (NC=64).
// --------------------------------------------------------------------------
__global__ __launch_bounds__(256) void carry_kernel(
    float* __restrict__ Aprod, const float* __restrict__ Hend)
{
  const int idx = blockIdx.x * 256 + threadIdx.x;  // over B*S*M
  const int b = idx / MS_;
  const int sm = idx - b * MS_;
  float h = 0.f;
  #pragma unroll 16
  for (int c = 0; c < NC; ++c) {
    const size_t o = ((size_t)b * NC + c) * MS_ + sm;
    const float a  = Aprod[o];
    const float he = Hend[o];
    Aprod[o] = h;                 // carry into chunk c
    h = fmaf(a, h, he);
  }
}

// --------------------------------------------------------------------------
extern "C" void kernel_launch(void* const* d_in, const int* in_sizes, int n_in,
                              void* d_out, int out_size, void* d_ws, size_t ws_size,
                              hipStream_t stream)
{
  const float* u     = (const float*)d_in[0];
  const float* delta = (const float*)d_in[1];
  const float* dt_w  = (const float*)d_in[2];
  const float* dt_b  = (const float*)d_in[3];
  const float* A_log = (const float*)d_in[4];
  const float* B_w   = (const float*)d_in[5];
  const float* C_w   = (const float*)d_in[6];
  const float* D     = (const float*)d_in[7];
  float* out = (float*)d_out;
  float* ws  = (float*)d_ws;

  const size_t fl_dt = (size_t)B_ * T_ * M_;   // 3,145,728
  const size_t fl_bc = (size_t)B_ * T_ * S_;   // 65,536
  const size_t fl_sm = (size_t)B_ * NC * MS_;  // 1,572,864

  float* dt_ws = ws;
  float* Bm    = dt_ws + fl_dt;
  float* Cm    = Bm + fl_bc;
  float* Aprod = Cm + fl_bc;         // later holds carries
  float* Hend  = Aprod + fl_sm;      // total ~25.7 MB

  dt_kernel<<<dim3(M_ / 64, (B_ * T_) / 64), 256, 0, stream>>>(delta, dt_w, dt_b, dt_ws);
  bc_kernel<<<dim3((B_ * T_) / 8), 512, 0, stream>>>(u, B_w, C_w, Bm, Cm);
  scan_v6<1><<<dim3(M_ / 64, NC, B_), 128, 0, stream>>>(
      dt_ws, u, Bm, Cm, A_log, D, Aprod, Hend, nullptr);
  carry_kernel<<<dim3((B_ * MS_) / 256), 256, 0, stream>>>(Aprod, Hend);
  scan_v6<3><<<dim3(M_ / 64, NC, B_), 128, 0, stream>>>(
      dt_ws, u, Bm, Cm, A_log, D, Aprod, Hend, out);
}